// Round 3
// baseline (63.944 us; speedup 1.0000x reference)
//
#include <hip/hip_runtime.h>
#include <stdint.h>

#define TLEN    96512
#define NBATCH  32
#define NFFT    512
#define KOUT    256
#define SHIFT   160
#define NFRAMES 601
#define FT      64            // f-tile per block
#define NK      32            // K-steps (512/16)
#define EPSF    1e-7f

typedef _Float16 f16;
typedef _Float16 half8 __attribute__((ext_vector_type(8)));
typedef float f32x16 __attribute__((ext_vector_type(16)));

// ---------------- workspace: W chunks, f16 hi/lo, pre-chunked + pre-swizzled --
// [ks][k][slot'] of 16B units; slot = (ri*2+hl)*2 + s, slot' = slot ^ (k&7)
#define WS_W_HALVES (NK * 256 * 64)       // 1 MB

// ---------------- LDS layout ----------------
#define LDS_W_OFF    0
#define W_BUF_BYTES  32768                 // one BK=16 chunk: 256k x 128B
#define LDS_X_OFF    (2 * W_BUF_BYTES)     // 65536
#define XSEG_PLANE   21504                 // 1344 x 16B units per hi/lo plane
#define LDS_RED_OFF  (LDS_X_OFF + 2 * XSEG_PLANE)   // 108544
#define LDS_STAT_OFF (LDS_RED_OFF + 4096)           // 16x32 float2
#define LDS_TOTAL    (LDS_STAT_OFF + 512)           // 113152 -> 1 block/CU

// ============ split W into f16 hi/lo, pre-chunked + pre-swizzled ============
__global__ __launch_bounds__(256) void split_w_kernel(
    const float* __restrict__ Wr, const float* __restrict__ Wi,
    f16* __restrict__ wsW)
{
    int id   = blockIdx.x * 256 + threadIdx.x;   // 65536 = 32ks * 256k * 8slots
    int ks   = id >> 11;
    int k    = (id >> 3) & 255;
    int slot = id & 7;
    int p  = slot >> 1, s = slot & 1;
    int ri = p >> 1, hl = p & 1;
    const float* src = (ri ? Wi : Wr) + k * NFFT + ks * 16 + s * 8;
    f16 vals[8];
    #pragma unroll
    for (int j = 0; j < 8; ++j) {
        float v = src[j];
        f16 h = (f16)v;
        f16 l = (f16)(v - (float)h);
        vals[j] = hl ? l : h;
    }
    int slotp = slot ^ (k & 7);
    *(half8*)(wsW + ((size_t)ks * 2048 + k * 8 + slotp) * 8) = *(half8*)vals;
}

// ============ async global->LDS 16B ============
typedef const __attribute__((address_space(1))) uint32_t g_u32;
typedef __attribute__((address_space(3))) uint32_t      l_u32;

__device__ inline void stage_w_chunk(const f16* __restrict__ wsW, char* smem,
                                     int ks, int w, int lane)
{
    const f16* g = wsW + (size_t)ks * (256 * 64);          // 32KB chunk
    char* base = smem + LDS_W_OFF + (ks & 1) * W_BUF_BYTES;
    #pragma unroll
    for (int it = 0; it < 4; ++it) {
        int chunk = it * 8 + w;                            // 32 x 1KB wave-chunks
        __builtin_amdgcn_global_load_lds((g_u32*)(g + chunk * 512 + lane * 8),
                                         (l_u32*)(base + chunk * 1024), 16, 0, 0);
    }
}

// ============ main MFMA kernel: 512 threads, 8 waves, wave = 32k x 64f ========
__global__ __launch_bounds__(512, 2) void dft_mfma_kernel(
    const f16* __restrict__ wsW, const float* __restrict__ x,
    float* __restrict__ out)
{
    __shared__ uint4 smem4[LDS_TOTAL / 16];
    char* smem = (char*)smem4;

    const int tid  = threadIdx.x;
    const int lane = tid & 63;
    const int w    = tid >> 6;         // wave 0..7, stacked along k
    const int l31  = lane & 31;
    const int lhi  = lane >> 5;
    const int b    = blockIdx.y;
    const int f0   = blockIdx.x * FT;
    const int kb   = w * 32;

    // ---- issue W chunk 0 (async), then stage+split x segment (f32 -> h/l) ----
    stage_w_chunk(wsW, smem, 0, w, lane);
    {
        const float* __restrict__ xb = x + (size_t)b * TLEN;
        for (int u = tid; u < XSEG_PLANE / 16; u += 512) {
            int s0 = f0 * SHIFT + u * 8;
            float v[8];
            if (s0 + 8 <= TLEN) {
                float4 p0 = *(const float4*)(xb + s0);
                float4 p1 = *(const float4*)(xb + s0 + 4);
                v[0]=p0.x; v[1]=p0.y; v[2]=p0.z; v[3]=p0.w;
                v[4]=p1.x; v[5]=p1.y; v[6]=p1.z; v[7]=p1.w;
            } else {
                #pragma unroll
                for (int j = 0; j < 8; ++j)
                    v[j] = (s0 + j < TLEN) ? xb[s0 + j] : 0.f;
            }
            f16 h[8], l[8];
            #pragma unroll
            for (int j = 0; j < 8; ++j) {
                h[j] = (f16)v[j];
                l[j] = (f16)(v[j] - (float)h[j]);
            }
            int up = u ^ ((u >> 3) & 7);           // 16B-unit XOR swizzle
            *(half8*)(smem + LDS_X_OFF + up * 16)              = *(half8*)h;
            *(half8*)(smem + LDS_X_OFF + XSEG_PLANE + up * 16) = *(half8*)l;
        }
    }
    __syncthreads();   // drains vmcnt (W0 landed) + lgkm (x staged)

    f32x16 acc[2][2] = {};   // [nf][ri]

    const int arow = kb + l31;
    int aoff[2][2];
    #pragma unroll
    for (int ri = 0; ri < 2; ++ri)
        #pragma unroll
        for (int hl = 0; hl < 2; ++hl) {
            int slot = ((((ri << 1) | hl) << 1) | lhi) ^ (arow & 7);
            aoff[ri][hl] = arow * 128 + slot * 16;
        }
    const int bu_base[2] = { l31 * 20 + lhi, (32 + l31) * 20 + lhi };

    for (int ks = 0; ks < NK; ++ks) {
        // stage next chunk into the OTHER buffer (its last readers were phase
        // ks-1, separated by the barrier below -> race-free)
        if (ks + 1 < NK) stage_w_chunk(wsW, smem, ks + 1, w, lane);

        const char* wb = smem + LDS_W_OFF + (ks & 1) * W_BUF_BYTES;
        half8 a[2][2], bb[2][2];
        #pragma unroll
        for (int ri = 0; ri < 2; ++ri)
            #pragma unroll
            for (int hl = 0; hl < 2; ++hl)
                a[ri][hl] = *(const half8*)(wb + aoff[ri][hl]);
        #pragma unroll
        for (int nf = 0; nf < 2; ++nf) {
            int u  = bu_base[nf] + ks * 2;
            int up = u ^ ((u >> 3) & 7);
            #pragma unroll
            for (int hl = 0; hl < 2; ++hl)
                bb[nf][hl] = *(const half8*)(smem + LDS_X_OFF + hl * XSEG_PLANE + up * 16);
        }

        #pragma unroll
        for (int nf = 0; nf < 2; ++nf)
            #pragma unroll
            for (int ri = 0; ri < 2; ++ri) {
                acc[nf][ri] = __builtin_amdgcn_mfma_f32_32x32x16_f16(
                    a[ri][0], bb[nf][0], acc[nf][ri], 0, 0, 0);   // hh
                acc[nf][ri] = __builtin_amdgcn_mfma_f32_32x32x16_f16(
                    a[ri][0], bb[nf][1], acc[nf][ri], 0, 0, 0);   // h*l
                acc[nf][ri] = __builtin_amdgcn_mfma_f32_32x32x16_f16(
                    a[ri][1], bb[nf][0], acc[nf][ri], 0, 0, 0);   // l*h
            }

        __syncthreads();   // drain: chunk ks+1 landed; all waves done with buf[ks&1]
    }

    // ---- epilogue: log-magnitude + per-(b,f) mean/std over k ----
    const float C = 0.15051499783199057f;      // 0.5*log10(2)
    float lg[2][16];
    float s1[2] = {0.f, 0.f}, s2[2] = {0.f, 0.f};
    #pragma unroll
    for (int nf = 0; nf < 2; ++nf)
        #pragma unroll
        for (int r = 0; r < 16; ++r) {
            float re = acc[nf][0][r], im = acc[nf][1][r];
            float lv = C * __log2f(re * re + im * im + EPSF);
            lg[nf][r] = lv;
            s1[nf] += lv;
            s2[nf] += lv * lv;
        }
    #pragma unroll
    for (int nf = 0; nf < 2; ++nf) {           // fold lanes l <-> l+32 (same f col)
        s1[nf] += __shfl_xor(s1[nf], 32);
        s2[nf] += __shfl_xor(s2[nf], 32);
    }
    float2* red = (float2*)(smem + LDS_RED_OFF);
    if (lane < 32) {
        red[(w * 2 + 0) * 32 + l31] = make_float2(s1[0], s2[0]);
        red[(w * 2 + 1) * 32 + l31] = make_float2(s1[1], s2[1]);
    }
    __syncthreads();
    float* stat = (float*)(smem + LDS_STAT_OFF);   // mean[64], rstd[64]
    if (tid < 64) {
        float S1 = 0.f, S2 = 0.f;
        int nf = tid >> 5, c = tid & 31;
        #pragma unroll
        for (int ww = 0; ww < 8; ++ww) {
            float2 p = red[(ww * 2 + nf) * 32 + c];
            S1 += p.x; S2 += p.y;
        }
        float mean = S1 * (1.f / 256.f);
        float var  = fmaxf(S2 * (1.f / 256.f) - mean * mean, 0.f);
        stat[tid]      = mean;
        stat[64 + tid] = 1.f / (__builtin_sqrtf(var) + EPSF);
    }
    __syncthreads();

    #pragma unroll
    for (int nf = 0; nf < 2; ++nf) {
        int fl = nf * 32 + l31;
        int f  = f0 + fl;
        if (f >= NFRAMES) continue;
        float mean = stat[fl], rstd = stat[64 + fl];
        #pragma unroll
        for (int r = 0; r < 16; ++r) {
            int k = kb + (r & 3) + ((r >> 2) << 3) + (lhi << 2);
            out[((size_t)b * KOUT + k) * NFRAMES + f] = (lg[nf][r] - mean) * rstd;
        }
    }
}

extern "C" void kernel_launch(void* const* d_in, const int* in_sizes, int n_in,
                              void* d_out, int out_size, void* d_ws, size_t ws_size,
                              hipStream_t stream) {
    const float* x  = (const float*)d_in[0];
    const float* Wr = (const float*)d_in[1];
    const float* Wi = (const float*)d_in[2];
    float* out = (float*)d_out;

    f16* wsW = (f16*)d_ws;

    split_w_kernel<<<256, 256, 0, stream>>>(Wr, Wi, wsW);

    dim3 grid((NFRAMES + FT - 1) / FT, NBATCH);   // 10 x 32
    dft_mfma_kernel<<<grid, 512, 0, stream>>>(wsW, x, out);
}

// Round 4
// 37.397 us; speedup vs baseline: 1.7098x; 1.7098x over previous
//
#include <hip/hip_runtime.h>
#include <stdint.h>

#define TLEN    96512
#define NBATCH  32
#define KOUT    256
#define SHIFT   160
#define NFRAMES 601
#define FT      61            // frames per block (61*10 = 610 >= 601)
#define NTILES  10
#define NKS     16            // K-steps of 16 over folded K=256
#define EPSF    1e-7f

typedef _Float16 f16;
typedef _Float16 half8 __attribute__((ext_vector_type(8)));
typedef float f32x16 __attribute__((ext_vector_type(16)));

// E/O stream span per f-tile: (FT-1)*160 + 256 samples
#define SPAN      ((FT - 1) * SHIFT + 256)   // 9856
#define UNITS     (SPAN / 8)                 // 1232 16B-units per plane
#define PLANE_B   (UNITS * 16)               // 19712 B
#define LDS_RED   (4 * PLANE_B)              // 78848
#define LDS_STAT  (LDS_RED + 2048)           // 80896
#define LDS_TOTAL (LDS_STAT + 512)           // 81408 -> 2 blocks/CU

// ============================================================================
// W' workspace: radix-2 folded, f16 hi/lo, MFMA-fragment-ready.
// chunk c = ((par*4 + J)*16 + ks)*4 + ri*2 + hl   (512 chunks x 1KB = 512 KB)
// within chunk: lane (l31,lhi) at halves offset (l31*2+lhi)*8  (16B, coalesced)
// A-value = W[k][n], k = 2*(J*32+l31)+par, n = ks*16 + lhi*8   (n < 256 only)
// ============================================================================
__global__ __launch_bounds__(256) void split_w_kernel(
    const float* __restrict__ Wr, const float* __restrict__ Wi,
    f16* __restrict__ wsW)
{
    int id   = blockIdx.x * 256 + threadIdx.x;   // 32768 threads
    int lane = id & 63;
    int hl   = (id >> 6) & 1;
    int ri   = (id >> 7) & 1;
    int ks   = (id >> 8) & 15;
    int J    = (id >> 12) & 3;
    int par  = (id >> 14) & 1;
    int l31  = lane & 31, lhi = lane >> 5;
    int k = 2 * (J * 32 + l31) + par;
    int n = ks * 16 + lhi * 8;
    const float* src = (ri ? Wi : Wr) + k * 512 + n;
    f16 v[8];
    #pragma unroll
    for (int j = 0; j < 8; ++j) {
        float xv = src[j];
        f16 h = (f16)xv;
        v[j] = hl ? (f16)(xv - (float)h) : h;
    }
    int c = ((par * 4 + J) * 16 + ks) * 4 + ri * 2 + hl;
    *(half8*)(wsW + (size_t)c * 512 + (l31 * 2 + lhi) * 8) = *(half8*)v;
}

// ---------------- K-loop helpers (all indices compile-time after unroll) ----
__device__ __forceinline__ void load_a(half8 (&a)[2][2][2],
    const f16* __restrict__ wsW, int par, int jb2, int laneoff, int ks)
{
    #pragma unroll
    for (int m = 0; m < 2; ++m)
      #pragma unroll
      for (int ri = 0; ri < 2; ++ri)
        #pragma unroll
        for (int hl = 0; hl < 2; ++hl) {
            int c = ((par * 4 + jb2 + m) * 16 + ks) * 4 + ri * 2 + hl;
            a[m][ri][hl] = *(const half8*)(wsW + (size_t)c * 512 + laneoff);
        }
}

__device__ __forceinline__ void load_b(half8 (&bb)[2][2],
    const char* smem, int par, int l31, int lhi, int ks)
{
    #pragma unroll
    for (int nf = 0; nf < 2; ++nf)
      #pragma unroll
      for (int hl = 0; hl < 2; ++hl) {
          int u  = (nf * 32 + l31) * 20 + ks * 2 + lhi;
          int up = u ^ ((u >> 3) & 7);
          bb[nf][hl] = *(const half8*)(smem + (par * 2 + hl) * PLANE_B + up * 16);
      }
}

__device__ __forceinline__ void do_mfma(f32x16 (&acc)[2][2][2],
    const half8 (&a)[2][2][2], const half8 (&bb)[2][2])
{
    #pragma unroll
    for (int m = 0; m < 2; ++m)
      #pragma unroll
      for (int nf = 0; nf < 2; ++nf)
        #pragma unroll
        for (int ri = 0; ri < 2; ++ri) {
            acc[m][nf][ri] = __builtin_amdgcn_mfma_f32_32x32x16_f16(
                a[m][ri][0], bb[nf][0], acc[m][nf][ri], 0, 0, 0);   // hh
            acc[m][nf][ri] = __builtin_amdgcn_mfma_f32_32x32x16_f16(
                a[m][ri][0], bb[nf][1], acc[m][nf][ri], 0, 0, 0);   // h*l
            acc[m][nf][ri] = __builtin_amdgcn_mfma_f32_32x32x16_f16(
                a[m][ri][1], bb[nf][0], acc[m][nf][ri], 0, 0, 0);   // l*h
        }
}

// ============================================================================
// Main kernel: 256 thr = 4 waves; wave = 64 k-rows (one parity) x 64 f-cols.
// A from global (L2-resident W', reg-double-buffered). B from LDS (read-only
// after stage). K-loop has NO barriers.
// ============================================================================
__global__ __launch_bounds__(256, 2) void dft_mfma_kernel(
    const f16* __restrict__ wsW, const float* __restrict__ x,
    float* __restrict__ out)
{
    __shared__ uint4 smem4[LDS_TOTAL / 16];
    char* smem = (char*)smem4;

    const int tid  = threadIdx.x;
    const int lane = tid & 63;
    const int w    = tid >> 6;      // 0..3
    const int l31  = lane & 31;
    const int lhi  = lane >> 5;
    const int b    = blockIdx.y;
    const int f0   = blockIdx.x * FT;
    const int par  = w & 1;         // k parity
    const int jb2  = (w >> 1) * 2;  // J base (J = jb2 + m)
    const int laneoff = (l31 * 2 + lhi) * 8;   // halves

    // ---- prefetch A(ks=0) early: global loads overlap the staging loop ----
    half8 a0[2][2][2], a1[2][2][2], b0[2][2], b1[2][2];
    load_a(a0, wsW, par, jb2, laneoff, 0);

    // ---- stage E/O hi/lo planes (one-time) ----
    {
        const float* __restrict__ xb = x + (size_t)b * TLEN;
        const int t0 = f0 * SHIFT;
        for (int u = tid; u < UNITS; u += 256) {
            int t = t0 + u * 8;
            float va[8], vb[8];
            if (t + 264 <= TLEN) {
                float4 p0 = *(const float4*)(xb + t);
                float4 p1 = *(const float4*)(xb + t + 4);
                float4 q0 = *(const float4*)(xb + t + 256);
                float4 q1 = *(const float4*)(xb + t + 260);
                va[0]=p0.x; va[1]=p0.y; va[2]=p0.z; va[3]=p0.w;
                va[4]=p1.x; va[5]=p1.y; va[6]=p1.z; va[7]=p1.w;
                vb[0]=q0.x; vb[1]=q0.y; vb[2]=q0.z; vb[3]=q0.w;
                vb[4]=q1.x; vb[5]=q1.y; vb[6]=q1.z; vb[7]=q1.w;
            } else {
                #pragma unroll
                for (int j = 0; j < 8; ++j) {
                    int ta = t + j, tb = t + 256 + j;
                    va[j] = (ta < TLEN) ? xb[ta] : 0.f;
                    vb[j] = (tb < TLEN) ? xb[tb] : 0.f;
                }
            }
            f16 eh[8], el[8], oh[8], ol[8];
            #pragma unroll
            for (int j = 0; j < 8; ++j) {
                float E = va[j] + vb[j], O = va[j] - vb[j];
                eh[j] = (f16)E; el[j] = (f16)(E - (float)eh[j]);
                oh[j] = (f16)O; ol[j] = (f16)(O - (float)oh[j]);
            }
            int up = u ^ ((u >> 3) & 7);
            *(half8*)(smem + 0 * PLANE_B + up * 16) = *(half8*)eh;
            *(half8*)(smem + 1 * PLANE_B + up * 16) = *(half8*)el;
            *(half8*)(smem + 2 * PLANE_B + up * 16) = *(half8*)oh;
            *(half8*)(smem + 3 * PLANE_B + up * 16) = *(half8*)ol;
        }
    }
    __syncthreads();    // the ONLY barrier before the epilogue

    f32x16 acc[2][2][2] = {};    // [m][nf][ri]
    load_b(b0, smem, par, l31, lhi, 0);

    #pragma unroll
    for (int ks2 = 0; ks2 < NKS; ks2 += 2) {
        load_a(a1, wsW, par, jb2, laneoff, ks2 + 1);
        load_b(b1, smem, par, l31, lhi, ks2 + 1);
        do_mfma(acc, a0, b0);
        int k2 = (ks2 + 2 < NKS) ? ks2 + 2 : NKS - 1;   // tail: redundant reload
        load_a(a0, wsW, par, jb2, laneoff, k2);
        load_b(b0, smem, par, l31, lhi, k2);
        do_mfma(acc, a1, b1);
    }

    // ---- epilogue: log-magnitude + per-(b,f) mean/std over k ----
    const float C = 0.15051499783199057f;    // 0.5*log10(2)
    float lg[2][2][16];
    float s1[2] = {0.f, 0.f}, s2[2] = {0.f, 0.f};
    #pragma unroll
    for (int m = 0; m < 2; ++m)
      #pragma unroll
      for (int nf = 0; nf < 2; ++nf)
        #pragma unroll
        for (int r = 0; r < 16; ++r) {
            float re = acc[m][nf][0][r], im = acc[m][nf][1][r];
            float lv = C * __log2f(re * re + im * im + EPSF);
            lg[m][nf][r] = lv;
            s1[nf] += lv;
            s2[nf] += lv * lv;
        }
    #pragma unroll
    for (int nf = 0; nf < 2; ++nf) {        // fold lanes l <-> l+32 (same f col)
        s1[nf] += __shfl_xor(s1[nf], 32);
        s2[nf] += __shfl_xor(s2[nf], 32);
    }
    float2* red = (float2*)(smem + LDS_RED);
    if (lane < 32) {
        red[(w * 2 + 0) * 32 + l31] = make_float2(s1[0], s2[0]);
        red[(w * 2 + 1) * 32 + l31] = make_float2(s1[1], s2[1]);
    }
    __syncthreads();
    float* stat = (float*)(smem + LDS_STAT);    // mean[64], rstd[64]
    if (tid < 64) {
        float S1 = 0.f, S2 = 0.f;
        int nf = tid >> 5, c = tid & 31;
        #pragma unroll
        for (int ww = 0; ww < 4; ++ww) {
            float2 p = red[(ww * 2 + nf) * 32 + c];
            S1 += p.x; S2 += p.y;
        }
        float mean = S1 * (1.f / 256.f);
        float var  = fmaxf(S2 * (1.f / 256.f) - mean * mean, 0.f);
        stat[tid]      = mean;
        stat[64 + tid] = 1.f / (__builtin_sqrtf(var) + EPSF);
    }
    __syncthreads();

    #pragma unroll
    for (int nf = 0; nf < 2; ++nf) {
        int fl = nf * 32 + l31;
        int f  = f0 + fl;
        if (fl >= FT || f >= NFRAMES) continue;   // cols >= FT are garbage
        float mean = stat[fl], rstd = stat[64 + fl];
        #pragma unroll
        for (int m = 0; m < 2; ++m)
          #pragma unroll
          for (int r = 0; r < 16; ++r) {
              int k = 2 * ((w >> 1) * 64 + m * 32 + (r & 3) + 8 * (r >> 2) + 4 * lhi) + par;
              out[((size_t)b * KOUT + k) * NFRAMES + f] = (lg[m][nf][r] - mean) * rstd;
          }
    }
}

extern "C" void kernel_launch(void* const* d_in, const int* in_sizes, int n_in,
                              void* d_out, int out_size, void* d_ws, size_t ws_size,
                              hipStream_t stream) {
    const float* x  = (const float*)d_in[0];
    const float* Wr = (const float*)d_in[1];
    const float* Wi = (const float*)d_in[2];
    float* out = (float*)d_out;

    f16* wsW = (f16*)d_ws;   // 512 KB

    split_w_kernel<<<128, 256, 0, stream>>>(Wr, Wi, wsW);

    dim3 grid(NTILES, NBATCH);   // 10 x 32 = 320 blocks, all co-resident
    dft_mfma_kernel<<<grid, 256, 0, stream>>>(wsW, x, out);
}

// Round 5
// 33.925 us; speedup vs baseline: 1.8849x; 1.1024x over previous
//
#include <hip/hip_runtime.h>
#include <stdint.h>

#define TLEN    96512
#define NBATCH  32
#define KOUT    256
#define SHIFT   160
#define NFRAMES 601
#define FT      76            // frames per block (76*8 = 608 >= 601)
#define NTILES  8
#define NKS     16            // K-steps of 16 over folded K=256
#define EPSF    1e-7f

typedef _Float16 f16;
typedef _Float16 half8 __attribute__((ext_vector_type(8)));
typedef float f32x16 __attribute__((ext_vector_type(16)));

// E/O stream span per f-tile: (FT-1)*160 + 256 samples
#define SPAN       ((FT - 1) * SHIFT + 256)   // 12256
#define UNITS      (SPAN / 8)                 // 1532 16B-units (real data)
#define PLANE_B    24576                      // plane stride (1536 units, padded)
#define LDS_RED    104768                     // 3*PLANE_B + slack for col>=FT reads
#define LDS_STAT   (LDS_RED + 6144)           // 8w x 3nf x 32 float2
#define LDS_TOTAL  (LDS_STAT + 768)           // 111680 -> 1 block/CU

// ============================================================================
// W' workspace: radix-2 folded, f16 hi/lo, MFMA-fragment-ready. 512 KB.
// chunk c = ((par*4 + J)*16 + ks)*4 + ri*2 + hl   (512 chunks x 1KB)
// within chunk: lane (l31,lhi) at halves offset (l31*2+lhi)*8  (16B, coalesced)
// A-value = W[k][n], k = 2*(J*32+l31)+par, n = ks*16 + lhi*8   (n < 256)
// ============================================================================
__global__ __launch_bounds__(256) void split_w_kernel(
    const float* __restrict__ Wr, const float* __restrict__ Wi,
    f16* __restrict__ wsW)
{
    int id   = blockIdx.x * 256 + threadIdx.x;   // 32768 threads
    int lane = id & 63;
    int hl   = (id >> 6) & 1;
    int ri   = (id >> 7) & 1;
    int ks   = (id >> 8) & 15;
    int J    = (id >> 12) & 3;
    int par  = (id >> 14) & 1;
    int l31  = lane & 31, lhi = lane >> 5;
    int k = 2 * (J * 32 + l31) + par;
    int n = ks * 16 + lhi * 8;
    const float* src = (ri ? Wi : Wr) + k * 512 + n;
    f16 v[8];
    #pragma unroll
    for (int j = 0; j < 8; ++j) {
        float xv = src[j];
        f16 h = (f16)xv;
        v[j] = hl ? (f16)(xv - (float)h) : h;
    }
    int c = ((par * 4 + J) * 16 + ks) * 4 + ri * 2 + hl;
    *(half8*)(wsW + (size_t)c * 512 + (l31 * 2 + lhi) * 8) = *(half8*)v;
}

// ---------------- K-loop helpers (all indices compile-time after unroll) ----
__device__ __forceinline__ void load_a(half8 (&a)[2][2],
    const f16* __restrict__ wsW, int par, int J, int laneoff, int ks)
{
    #pragma unroll
    for (int ri = 0; ri < 2; ++ri)
      #pragma unroll
      for (int hl = 0; hl < 2; ++hl) {
          int c = ((par * 4 + J) * 16 + ks) * 4 + ri * 2 + hl;
          a[ri][hl] = *(const half8*)(wsW + (size_t)c * 512 + laneoff);
      }
}

__device__ __forceinline__ void load_b(half8 (&bb)[3][2],
    const char* smem, int par, int l31, int lhi, int ks)
{
    #pragma unroll
    for (int nf = 0; nf < 3; ++nf)
      #pragma unroll
      for (int hl = 0; hl < 2; ++hl) {
          int u  = (nf * 32 + l31) * 20 + ks * 2 + lhi;
          int up = u ^ ((u >> 3) & 7);
          bb[nf][hl] = *(const half8*)(smem + (par * 2 + hl) * PLANE_B + up * 16);
      }
}

__device__ __forceinline__ void do_mfma(f32x16 (&acc)[3][2],
    const half8 (&a)[2][2], const half8 (&bb)[3][2])
{
    #pragma unroll
    for (int nf = 0; nf < 3; ++nf)
      #pragma unroll
      for (int ri = 0; ri < 2; ++ri) {
          acc[nf][ri] = __builtin_amdgcn_mfma_f32_32x32x16_f16(
              a[ri][0], bb[nf][0], acc[nf][ri], 0, 0, 0);   // hh
          acc[nf][ri] = __builtin_amdgcn_mfma_f32_32x32x16_f16(
              a[ri][0], bb[nf][1], acc[nf][ri], 0, 0, 0);   // h*l
          acc[nf][ri] = __builtin_amdgcn_mfma_f32_32x32x16_f16(
              a[ri][1], bb[nf][0], acc[nf][ri], 0, 0, 0);   // l*h
      }
}

// ============================================================================
// Main kernel: 512 thr = 8 waves; wave = 32 k-rows (one parity) x 96 f-cols.
// Grid 8x32 = 256 blocks = exactly 1 per CU (perfect balance, zero tail).
// A from global (L2-resident W', reg-double-buffered). B from LDS (read-only
// after stage). K-loop has NO barriers.
// ============================================================================
__global__ __launch_bounds__(512, 2) void dft_mfma_kernel(
    const f16* __restrict__ wsW, const float* __restrict__ x,
    float* __restrict__ out)
{
    __shared__ uint4 smem4[LDS_TOTAL / 16];
    char* smem = (char*)smem4;

    const int tid  = threadIdx.x;
    const int lane = tid & 63;
    const int w    = tid >> 6;      // 0..7
    const int l31  = lane & 31;
    const int lhi  = lane >> 5;
    const int b    = blockIdx.y;
    const int f0   = blockIdx.x * FT;
    const int par  = w & 1;         // k parity (0 -> E planes, 1 -> O planes)
    const int J    = w >> 1;        // 0..3
    const int laneoff = (l31 * 2 + lhi) * 8;   // halves

    // ---- prefetch A(ks=0) early: global loads overlap the staging loop ----
    half8 a0[2][2], a1[2][2], b0[3][2], b1[3][2];
    load_a(a0, wsW, par, J, laneoff, 0);

    // ---- stage E/O hi/lo planes (one-time) ----
    {
        const float* __restrict__ xb = x + (size_t)b * TLEN;
        const int t0 = f0 * SHIFT;
        for (int u = tid; u < UNITS; u += 512) {
            int t = t0 + u * 8;
            float va[8], vb[8];
            if (t + 264 <= TLEN) {
                float4 p0 = *(const float4*)(xb + t);
                float4 p1 = *(const float4*)(xb + t + 4);
                float4 q0 = *(const float4*)(xb + t + 256);
                float4 q1 = *(const float4*)(xb + t + 260);
                va[0]=p0.x; va[1]=p0.y; va[2]=p0.z; va[3]=p0.w;
                va[4]=p1.x; va[5]=p1.y; va[6]=p1.z; va[7]=p1.w;
                vb[0]=q0.x; vb[1]=q0.y; vb[2]=q0.z; vb[3]=q0.w;
                vb[4]=q1.x; vb[5]=q1.y; vb[6]=q1.z; vb[7]=q1.w;
            } else {
                #pragma unroll
                for (int j = 0; j < 8; ++j) {
                    int ta = t + j, tb = t + 256 + j;
                    va[j] = (ta < TLEN) ? xb[ta] : 0.f;
                    vb[j] = (tb < TLEN) ? xb[tb] : 0.f;
                }
            }
            f16 eh[8], el[8], oh[8], ol[8];
            #pragma unroll
            for (int j = 0; j < 8; ++j) {
                float E = va[j] + vb[j], O = va[j] - vb[j];
                eh[j] = (f16)E; el[j] = (f16)(E - (float)eh[j]);
                oh[j] = (f16)O; ol[j] = (f16)(O - (float)oh[j]);
            }
            int up = u ^ ((u >> 3) & 7);
            *(half8*)(smem + 0 * PLANE_B + up * 16) = *(half8*)eh;
            *(half8*)(smem + 1 * PLANE_B + up * 16) = *(half8*)el;
            *(half8*)(smem + 2 * PLANE_B + up * 16) = *(half8*)oh;
            *(half8*)(smem + 3 * PLANE_B + up * 16) = *(half8*)ol;
        }
    }
    __syncthreads();    // the ONLY barrier before the epilogue

    f32x16 acc[3][2] = {};    // [nf][ri]
    load_b(b0, smem, par, l31, lhi, 0);

    #pragma unroll
    for (int ks2 = 0; ks2 < NKS; ks2 += 2) {
        load_a(a1, wsW, par, J, laneoff, ks2 + 1);
        load_b(b1, smem, par, l31, lhi, ks2 + 1);
        do_mfma(acc, a0, b0);
        int k2 = (ks2 + 2 < NKS) ? ks2 + 2 : NKS - 1;   // tail: redundant reload
        load_a(a0, wsW, par, J, laneoff, k2);
        load_b(b0, smem, par, l31, lhi, k2);
        do_mfma(acc, a1, b1);
    }

    // ---- epilogue: log-magnitude + per-(b,f) mean/std over k ----
    const float C = 0.15051499783199057f;    // 0.5*log10(2)
    float lg[3][16];
    float s1[3] = {0.f, 0.f, 0.f}, s2[3] = {0.f, 0.f, 0.f};
    #pragma unroll
    for (int nf = 0; nf < 3; ++nf)
      #pragma unroll
      for (int r = 0; r < 16; ++r) {
          float re = acc[nf][0][r], im = acc[nf][1][r];
          float lv = C * __log2f(re * re + im * im + EPSF);
          lg[nf][r] = lv;
          s1[nf] += lv;
          s2[nf] += lv * lv;
      }
    #pragma unroll
    for (int nf = 0; nf < 3; ++nf) {        // fold lanes l <-> l+32 (same f col)
        s1[nf] += __shfl_xor(s1[nf], 32);
        s2[nf] += __shfl_xor(s2[nf], 32);
    }
    float2* red = (float2*)(smem + LDS_RED);
    if (lane < 32) {
        #pragma unroll
        for (int nf = 0; nf < 3; ++nf)
            red[(w * 3 + nf) * 32 + l31] = make_float2(s1[nf], s2[nf]);
    }
    __syncthreads();
    float* stat = (float*)(smem + LDS_STAT);    // mean[96], rstd[96]
    if (tid < 96) {
        float S1 = 0.f, S2 = 0.f;
        int nf = tid >> 5, c = tid & 31;
        #pragma unroll
        for (int ww = 0; ww < 8; ++ww) {
            float2 p = red[(ww * 3 + nf) * 32 + c];
            S1 += p.x; S2 += p.y;
        }
        float mean = S1 * (1.f / 256.f);
        float var  = fmaxf(S2 * (1.f / 256.f) - mean * mean, 0.f);
        stat[tid]      = mean;
        stat[96 + tid] = 1.f / (__builtin_sqrtf(var) + EPSF);
    }
    __syncthreads();

    #pragma unroll
    for (int nf = 0; nf < 3; ++nf) {
        int fl = nf * 32 + l31;
        int f  = f0 + fl;
        if (fl >= FT || f >= NFRAMES) continue;   // cols >= FT are garbage
        float mean = stat[fl], rstd = stat[96 + fl];
        #pragma unroll
        for (int r = 0; r < 16; ++r) {
            int k = 2 * (J * 32 + (r & 3) + 8 * (r >> 2) + 4 * lhi) + par;
            out[((size_t)b * KOUT + k) * NFRAMES + f] = (lg[nf][r] - mean) * rstd;
        }
    }
}

extern "C" void kernel_launch(void* const* d_in, const int* in_sizes, int n_in,
                              void* d_out, int out_size, void* d_ws, size_t ws_size,
                              hipStream_t stream) {
    const float* x  = (const float*)d_in[0];
    const float* Wr = (const float*)d_in[1];
    const float* Wi = (const float*)d_in[2];
    float* out = (float*)d_out;

    f16* wsW = (f16*)d_ws;   // 512 KB

    split_w_kernel<<<128, 256, 0, stream>>>(Wr, Wi, wsW);

    dim3 grid(NTILES, NBATCH);   // 8 x 32 = 256 blocks, 1 per CU
    dft_mfma_kernel<<<grid, 512, 0, stream>>>(wsW, x, out);
}